// Round 12
// baseline (101.768 us; speedup 1.0000x reference)
//
#include <hip/hip_runtime.h>

// SS2D: B=32,H=32,W=32,DM=128, DIN=64, N=16, R=8, L=1024
// Layouts: xc,u,delta,y = (b,d,l); z = (b,l,d); Bs,Cs = (b,n,l); out = (b,l,dm)

// ---------------- K1: xz = x @ w_in^T ; split into xc (NCHW) and z (b,l,d) ----
__global__ __launch_bounds__(256) void k1_gemm_in(
    const float* __restrict__ x, const float* __restrict__ w_in,
    float* __restrict__ xc, float* __restrict__ z)
{
    __shared__ float As[32 * 68];    // [k][m], stride 68
    __shared__ float Ws[32 * 132];   // [k][e], stride 132
    const int t  = threadIdx.x;
    const int p0 = blockIdx.x * 64;
    const int tx = t & 15, ty = t >> 4;

    float acc[4][8];
#pragma unroll
    for (int i = 0; i < 4; ++i)
#pragma unroll
        for (int j = 0; j < 8; ++j) acc[i][j] = 0.f;

    for (int kk = 0; kk < 128; kk += 32) {
        {
            const int m  = t >> 3;
            const int c4 = (t & 7) * 4;
            const float4 v0 = *reinterpret_cast<const float4*>(&x[(size_t)(p0 + m) * 128 + kk + c4]);
            const float4 v1 = *reinterpret_cast<const float4*>(&x[(size_t)(p0 + m + 32) * 128 + kk + c4]);
            As[(c4 + 0) * 68 + m] = v0.x; As[(c4 + 1) * 68 + m] = v0.y;
            As[(c4 + 2) * 68 + m] = v0.z; As[(c4 + 3) * 68 + m] = v0.w;
            As[(c4 + 0) * 68 + m + 32] = v1.x; As[(c4 + 1) * 68 + m + 32] = v1.y;
            As[(c4 + 2) * 68 + m + 32] = v1.z; As[(c4 + 3) * 68 + m + 32] = v1.w;
        }
        for (int i = t; i < 4096; i += 256) {
            const int c = i & 31, e = i >> 5;
            Ws[c * 132 + e] = w_in[(size_t)e * 128 + kk + c];
        }
        __syncthreads();
#pragma unroll
        for (int k = 0; k < 32; ++k) {
            const float4 a  = *reinterpret_cast<const float4*>(&As[k * 68 + (ty << 2)]);
            const float4 b0 = *reinterpret_cast<const float4*>(&Ws[k * 132 + (tx << 3)]);
            const float4 b1 = *reinterpret_cast<const float4*>(&Ws[k * 132 + (tx << 3) + 4]);
            const float am[4] = {a.x, a.y, a.z, a.w};
            const float bm[8] = {b0.x, b0.y, b0.z, b0.w, b1.x, b1.y, b1.z, b1.w};
#pragma unroll
            for (int i = 0; i < 4; ++i)
#pragma unroll
                for (int j = 0; j < 8; ++j)
                    acc[i][j] = fmaf(am[i], bm[j], acc[i][j]);
        }
        __syncthreads();
    }

    const int b  = p0 >> 10;
    const int l0 = (p0 & 1023) + (ty << 2);
    if (tx < 8) {
#pragma unroll
        for (int j = 0; j < 8; ++j) {
            const int e = (tx << 3) + j;
            *reinterpret_cast<float4*>(&xc[((size_t)b * 64 + e) * 1024 + l0]) =
                make_float4(acc[0][j], acc[1][j], acc[2][j], acc[3][j]);
        }
    } else {
        const int d0 = (tx - 8) << 3;
#pragma unroll
        for (int i = 0; i < 4; ++i) {
            const size_t p = (size_t)p0 + (ty << 2) + i;
            *reinterpret_cast<float4*>(&z[p * 64 + d0]) =
                make_float4(acc[i][0], acc[i][1], acc[i][2], acc[i][3]);
            *reinterpret_cast<float4*>(&z[p * 64 + d0 + 4]) =
                make_float4(acc[i][4], acc[i][5], acc[i][6], acc[i][7]);
        }
    }
}

// ---------------- K2: depthwise 3x3 conv + bias + SiLU -> u (b,d,l) ----------
__global__ __launch_bounds__(256) void k2_conv(
    const float* __restrict__ xc, const float* __restrict__ cw,
    const float* __restrict__ cb, float* __restrict__ u)
{
    __shared__ float pl[1024];
    const int bd = blockIdx.x;
    const int t  = threadIdx.x;
    const int d  = bd & 63;
    reinterpret_cast<float4*>(pl)[t] =
        reinterpret_cast<const float4*>(xc + (size_t)bd * 1024)[t];
    float w[9];
#pragma unroll
    for (int i = 0; i < 9; ++i) w[i] = cw[d * 9 + i];
    const float bias = cb[d];
    __syncthreads();
    float o[4];
#pragma unroll
    for (int i = 0; i < 4; ++i) {
        const int p  = t * 4 + i;
        const int py = p >> 5, px = p & 31;
        float s = 0.f;
#pragma unroll
        for (int ky = 0; ky < 3; ++ky) {
            const int iy = py + ky - 1;
            if (iy < 0 || iy > 31) continue;
#pragma unroll
            for (int kx = 0; kx < 3; ++kx) {
                const int ix = px + kx - 1;
                if (ix < 0 || ix > 31) continue;
                s = fmaf(pl[iy * 32 + ix], w[ky * 3 + kx], s);
            }
        }
        s += bias;
        o[i] = s / (1.f + __expf(-s));
    }
    reinterpret_cast<float4*>(u + (size_t)bd * 1024)[t] = make_float4(o[0], o[1], o[2], o[3]);
}

// ---------------- K3: x-proj (40 ch) + dt-proj + softplus --------------------
// 1024 blocks x 64 threads; strip of 32 pixels. Thread = (pixq = t&7 -> 4
// pixels, cg = t>>3 -> 5 channels). Inner loop per dd: 1 ds_read_b128 (u) +
// 5 ds_read_b32 (w, bank-spread) for 20 outputs. B/C: direct coalesced
// float4 stores. Channels 0..7 -> xd8 LDS for the dt-proj (float4 stores).
__global__ __launch_bounds__(64) void k3_xproj(
    const float* __restrict__ u, const float* __restrict__ xpw,
    const float* __restrict__ dtw_g, const float* __restrict__ dtb,
    float* __restrict__ delta, float* __restrict__ Bsp, float* __restrict__ Csp)
{
    __shared__ float ut[64][36];   // [d][pix], pad 4
    __shared__ float xw[64 * 40];  // [d][ch]
    __shared__ float xd8[8][36];   // [ch<8][pix]
    __shared__ float dwv[64 * 9];  // [d][r] stride 9
    const int t   = threadIdx.x;
    const int blk = blockIdx.x;
    const int b   = blk >> 5;
    const int l0  = (blk & 31) * 32;

    // stage xw transposed: iteration c, lane t=dd reads coalesced row
#pragma unroll 4
    for (int c = 0; c < 40; ++c)
        xw[t * 40 + c] = xpw[(size_t)c * 64 + t];
    // stage dt weights (stride 9)
#pragma unroll
    for (int k = 0; k < 8; ++k)
        dwv[t * 9 + k] = dtw_g[t * 8 + k];
    // stage u tile (float4)
    {
        const float* ub = u + (size_t)b * 65536 + l0;
#pragma unroll
        for (int i = t; i < 512; i += 64) {
            const int dd = i >> 3, pq = i & 7;
            const float4 v = *reinterpret_cast<const float4*>(ub + (size_t)dd * 1024 + pq * 4);
            *reinterpret_cast<float4*>(&ut[dd][pq * 4]) = v;
        }
    }
    __syncthreads();

    const int pixq = t & 7;
    const int cg   = t >> 3;
    const int c0   = cg * 5;
    float4 acc[5];
#pragma unroll
    for (int j = 0; j < 5; ++j) acc[j] = make_float4(0.f, 0.f, 0.f, 0.f);
#pragma unroll 8
    for (int dd = 0; dd < 64; ++dd) {
        const float4 uv = *reinterpret_cast<const float4*>(&ut[dd][pixq * 4]);
        const float* row = &xw[dd * 40 + c0];
#pragma unroll
        for (int j = 0; j < 5; ++j) {
            const float w = row[j];
            acc[j].x = fmaf(w, uv.x, acc[j].x);
            acc[j].y = fmaf(w, uv.y, acc[j].y);
            acc[j].z = fmaf(w, uv.z, acc[j].z);
            acc[j].w = fmaf(w, uv.w, acc[j].w);
        }
    }
    // scatter: c<8 -> xd8 (LDS); 8..23 -> Bs; 24..39 -> Cs
#pragma unroll
    for (int j = 0; j < 5; ++j) {
        const int c = c0 + j;
        if (c < 8) {
            *reinterpret_cast<float4*>(&xd8[c][pixq * 4]) = acc[j];
        } else if (c < 24) {
            *reinterpret_cast<float4*>(Bsp + (size_t)b * 16384 +
                (size_t)(c - 8) * 1024 + l0 + pixq * 4) = acc[j];
        } else {
            *reinterpret_cast<float4*>(Csp + (size_t)b * 16384 +
                (size_t)(c - 24) * 1024 + l0 + pixq * 4) = acc[j];
        }
    }
    __syncthreads();

    // dt-proj + softplus: thread = (pixq, dg = t>>3 -> 8 d's)
    const int dg = t >> 3;
    float dts[4][8];
#pragma unroll
    for (int e = 0; e < 4; ++e)
#pragma unroll
        for (int r = 0; r < 8; ++r)
            dts[e][r] = xd8[r][pixq * 4 + e];
    float* dp = delta + (size_t)b * 65536 + l0 + pixq * 4;
#pragma unroll
    for (int k = 0; k < 8; ++k) {
        const int dd = dg * 8 + k;
        const float* r8 = &dwv[dd * 9];
        const float bias = dtb[dd];
        float ov[4];
#pragma unroll
        for (int e = 0; e < 4; ++e) {
            float s = bias;
#pragma unroll
            for (int r = 0; r < 8; ++r) s = fmaf(dts[e][r], r8[r], s);
            ov[e] = fmaxf(s, 0.f) + log1pf(__expf(-fabsf(s)));
        }
        *reinterpret_cast<float4*>(dp + (size_t)dd * 1024) =
            make_float4(ov[0], ov[1], ov[2], ov[3]);
    }
}

// ---------------- K4: timestep-major chunked scan (block per (b,d)) ----------
__global__ __launch_bounds__(256) void k4_scan(
    const float* __restrict__ delta, const float* __restrict__ u,
    const float* __restrict__ Bsp, const float* __restrict__ Csp,
    const float* __restrict__ A_logs, const float* __restrict__ Ds,
    float* __restrict__ y)
{
    __shared__ float Ps[256][17];
    __shared__ float qs[256][17];
    __shared__ float Sp[16][17];
    __shared__ float Sq[16][17];
    const int t = threadIdx.x;
    const int pair = blockIdx.x;    // b*64 + d
    const int b = pair >> 6, d = pair & 63;

    float A[16];
#pragma unroll
    for (int n = 0; n < 16; ++n) A[n] = -__expf(A_logs[d * 16 + n]);

    const float4 d4 = *reinterpret_cast<const float4*>(delta + (size_t)pair * 1024 + t * 4);
    const float4 u4 = *reinterpret_cast<const float4*>(u     + (size_t)pair * 1024 + t * 4);
    const float du0 = d4.x * u4.x, du1 = d4.y * u4.y;
    const float du2 = d4.z * u4.z, du3 = d4.w * u4.w;

    const float* Bb = Bsp + (size_t)b * 16384 + t * 4;
    const float* Cb = Csp + (size_t)b * 16384 + t * 4;

    // ---- phase A ----
#pragma unroll
    for (int n = 0; n < 16; ++n) {
        const float4 B4 = *reinterpret_cast<const float4*>(Bb + n * 1024);
        float a, P, q;
        a = __expf(d4.x * A[n]); P = a;   q = du0 * B4.x;
        a = __expf(d4.y * A[n]); P *= a;  q = fmaf(a, q, du1 * B4.y);
        a = __expf(d4.z * A[n]); P *= a;  q = fmaf(a, q, du2 * B4.z);
        a = __expf(d4.w * A[n]); P *= a;  q = fmaf(a, q, du3 * B4.w);
        Ps[t][n] = P; qs[t][n] = q;
    }
    __syncthreads();

    // ---- phase B ----
    const int n = t >> 4, g = t & 15;
    float rp[16], rq[16];
    {
        float Pseg = 1.f, qseg = 0.f;
#pragma unroll
        for (int i = 0; i < 16; ++i) {
            const int c = g * 16 + i;
            rp[i] = Ps[c][n]; rq[i] = qs[c][n];
            qseg = fmaf(rp[i], qseg, rq[i]);
            Pseg *= rp[i];
        }
        Sp[g][n] = Pseg; Sq[g][n] = qseg;
    }
    __syncthreads();
    if (t < 16) {
        float h = 0.f;
#pragma unroll
        for (int s = 0; s < 16; ++s) {
            const float Pv = Sp[s][t], qv = Sq[s][t];
            Sp[s][t] = h;
            h = fmaf(Pv, h, qv);
        }
    }
    __syncthreads();
    {
        float h = Sp[g][n];
#pragma unroll
        for (int i = 0; i < 16; ++i) {
            const int c = g * 16 + i;
            qs[c][n] = h;
            h = fmaf(rp[i], h, rq[i]);
        }
    }
    __syncthreads();

    // ---- phase C ----
    const float Dval = Ds[d];
    float y0 = Dval * u4.x, y1 = Dval * u4.y, y2 = Dval * u4.z, y3 = Dval * u4.w;
#pragma unroll
    for (int nn = 0; nn < 16; ++nn) {
        const float4 B4 = *reinterpret_cast<const float4*>(Bb + nn * 1024);
        const float4 C4 = *reinterpret_cast<const float4*>(Cb + nn * 1024);
        float h = qs[t][nn];
        float a;
        a = __expf(d4.x * A[nn]); h = fmaf(a, h, du0 * B4.x); y0 = fmaf(h, C4.x, y0);
        a = __expf(d4.y * A[nn]); h = fmaf(a, h, du1 * B4.y); y1 = fmaf(h, C4.y, y1);
        a = __expf(d4.z * A[nn]); h = fmaf(a, h, du2 * B4.z); y2 = fmaf(h, C4.z, y2);
        a = __expf(d4.w * A[nn]); h = fmaf(a, h, du3 * B4.w); y3 = fmaf(h, C4.w, y3);
    }
    *reinterpret_cast<float4*>(y + (size_t)pair * 1024 + t * 4) =
        make_float4(y0, y1, y2, y3);
}

// ---------------- K5: LayerNorm + silu(z) gate + out GEMM --------------------
__global__ __launch_bounds__(256) void k5_out(
    const float* __restrict__ y, const float* __restrict__ z,
    const float* __restrict__ ln_g, const float* __restrict__ ln_b,
    const float* __restrict__ w_out, float* __restrict__ out)
{
    __shared__ float yn[64 * 68];   // [l_local][d] stride 68
    __shared__ float wo[64 * 132];  // [d][c] pad 132
    const int t  = threadIdx.x;
    const int p0 = blockIdx.x * 64;
    const int b  = p0 >> 10, l0 = p0 & 1023;

    for (int i = t; i < 8192; i += 256) {
        const int c = i >> 6, dd = i & 63;
        wo[dd * 132 + c] = w_out[i];
    }

    {
        const int d = t >> 2;
        const float* yrow = y + ((size_t)b * 64 + d) * 1024 + l0;
#pragma unroll
        for (int k = 0; k < 4; ++k) {
            const int c4 = ((t & 3) + k * 4) * 4;
            const float4 v = *reinterpret_cast<const float4*>(&yrow[c4]);
            yn[(c4 + 0) * 68 + d] = v.x;
            yn[(c4 + 1) * 68 + d] = v.y;
            yn[(c4 + 2) * 68 + d] = v.z;
            yn[(c4 + 3) * 68 + d] = v.w;
        }
    }
    __syncthreads();

    const int lane = t & 63, wv = t >> 6;
    const float g = ln_g[lane], bbv = ln_b[lane];
#pragma unroll 1
    for (int i = 0; i < 16; ++i) {
        const int pl = wv * 16 + i;
        const size_t p = (size_t)p0 + pl;
        const float v  = yn[pl * 68 + lane];
        const float zv = z[p * 64 + lane];
        float s1 = v, s2 = v * v;
#pragma unroll
        for (int m = 1; m < 64; m <<= 1) {
            s1 += __shfl_xor(s1, m);
            s2 += __shfl_xor(s2, m);
        }
        const float mu   = s1 * (1.f / 64.f);
        const float var  = s2 * (1.f / 64.f) - mu * mu;
        const float rstd = rsqrtf(var + 1e-5f);
        const float sz   = zv / (1.f + __expf(-zv));
        yn[pl * 68 + lane] = ((v - mu) * rstd * g + bbv) * sz;
    }
    __syncthreads();

    const int tx = t & 31, ty = t >> 5;
    float acc[8][4];
#pragma unroll
    for (int i = 0; i < 8; ++i)
#pragma unroll
        for (int j = 0; j < 4; ++j) acc[i][j] = 0.f;

    for (int dd = 0; dd < 64; ++dd) {
        const float4 w4 = *reinterpret_cast<const float4*>(&wo[dd * 132 + (tx << 2)]);
#pragma unroll
        for (int i = 0; i < 8; ++i) {
            const float a = yn[(ty * 8 + i) * 68 + dd];
            acc[i][0] = fmaf(a, w4.x, acc[i][0]);
            acc[i][1] = fmaf(a, w4.y, acc[i][1]);
            acc[i][2] = fmaf(a, w4.z, acc[i][2]);
            acc[i][3] = fmaf(a, w4.w, acc[i][3]);
        }
    }
#pragma unroll
    for (int i = 0; i < 8; ++i) {
        const size_t p = (size_t)p0 + ty * 8 + i;
        *reinterpret_cast<float4*>(&out[p * 128 + (tx << 2)]) =
            make_float4(acc[i][0], acc[i][1], acc[i][2], acc[i][3]);
    }
}

extern "C" void kernel_launch(void* const* d_in, const int* in_sizes, int n_in,
                              void* d_out, int out_size, void* d_ws, size_t ws_size,
                              hipStream_t stream)
{
    const float* x        = (const float*)d_in[0];
    const float* w_in     = (const float*)d_in[1];
    const float* conv_w   = (const float*)d_in[2];
    const float* conv_b   = (const float*)d_in[3];
    const float* xproj_w  = (const float*)d_in[4];
    const float* dtproj_w = (const float*)d_in[5];
    const float* dtproj_b = (const float*)d_in[6];
    const float* A_logs   = (const float*)d_in[7];
    const float* Ds       = (const float*)d_in[8];
    const float* ln_g     = (const float*)d_in[9];
    const float* ln_b     = (const float*)d_in[10];
    const float* w_out    = (const float*)d_in[11];
    float* out = (float*)d_out;
    float* ws  = (float*)d_ws;

    const size_t M  = (size_t)2097152;  // 32*64*1024
    float* xc    = ws;                  // 8 MB
    float* z     = ws + M;              // 8 MB
    float* u     = ws + 2 * M;          // 8 MB
    float* delta = ws + 3 * M;          // 8 MB
    float* y     = ws + 4 * M;          // 8 MB  (b,d,l)
    float* Bsp   = ws + 5 * M;          // 2 MB
    float* Csp   = Bsp + 524288;        // 2 MB

    k1_gemm_in<<<512, 256, 0, stream>>>(x, w_in, xc, z);
    k2_conv<<<2048, 256, 0, stream>>>(xc, conv_w, conv_b, u);
    k3_xproj<<<1024, 64, 0, stream>>>(u, xproj_w, dtproj_w, dtproj_b, delta, Bsp, Csp);
    k4_scan<<<2048, 256, 0, stream>>>(delta, u, Bsp, Csp, A_logs, Ds, y);
    k5_out<<<512, 256, 0, stream>>>(y, z, ln_g, ln_b, w_out, out);
}